// Round 2
// baseline (228.416 us; speedup 1.0000x reference)
//
#include <hip/hip_runtime.h>
#include <math.h>

#define INDIM 128
#define HC 256
#define NH 4
#define CH 256
#define BROWS 40

// ---------------- GEMM: xp[n, hc] = sum_k x[n,k] * W[k,hc] ----------------
__global__ __launch_bounds__(256) void gemm_kernel(const float* __restrict__ x,
                                                   const float* __restrict__ W,
                                                   float* __restrict__ xp, int N) {
  constexpr int GN = 32;
  __shared__ float xs[GN * INDIM];
  int n0 = blockIdx.x * GN;
  int tid = threadIdx.x;
  int nrows = min(GN, N - n0);
  if (nrows == GN) {
    const float4* xg = (const float4*)(x + (size_t)n0 * INDIM);
    float4* xs4 = (float4*)xs;
    for (int i = tid; i < GN * INDIM / 4; i += 256) xs4[i] = xg[i];
  } else {
    for (int i = tid; i < GN * INDIM; i += 256) {
      int r = i / INDIM;
      xs[i] = (r < nrows) ? x[(size_t)(n0 + r) * INDIM + (i % INDIM)] : 0.f;
    }
  }
  __syncthreads();
  float acc[GN];
#pragma unroll
  for (int j = 0; j < GN; ++j) acc[j] = 0.f;
  for (int k0 = 0; k0 < INDIM; k0 += 4) {
    float w0 = W[(size_t)(k0 + 0) * HC + tid];
    float w1 = W[(size_t)(k0 + 1) * HC + tid];
    float w2 = W[(size_t)(k0 + 2) * HC + tid];
    float w3 = W[(size_t)(k0 + 3) * HC + tid];
#pragma unroll
    for (int j = 0; j < GN; ++j) {
      float4 xv = *(const float4*)&xs[j * INDIM + k0];
      acc[j] = fmaf(xv.w, w3, fmaf(xv.z, w2, fmaf(xv.y, w1, fmaf(xv.x, w0, acc[j]))));
    }
  }
  for (int j = 0; j < nrows; ++j) xp[(size_t)(n0 + j) * HC + tid] = acc[j];
}

// ------------- per-node attention coefficients a_src/a_dst [N,H] -------------
__global__ __launch_bounds__(256) void att_kernel(const float* __restrict__ xp,
                                                  const float* __restrict__ att_s,
                                                  const float* __restrict__ att_d,
                                                  float* __restrict__ a_src,
                                                  float* __restrict__ a_dst, int N) {
  int n = blockIdx.x * 4 + (threadIdx.x >> 6);
  int lane = threadIdx.x & 63;
  if (n >= N) return;
  const float* row = xp + (size_t)n * HC;
#pragma unroll
  for (int h = 0; h < NH; ++h) {
    float v = row[h * 64 + lane];
    float ps = v * att_s[h * 64 + lane];
    float pd = v * att_d[h * 64 + lane];
#pragma unroll
    for (int o = 32; o > 0; o >>= 1) {
      ps += __shfl_xor(ps, o);
      pd += __shfl_xor(pd, o);
    }
    if (lane == 0) {
      a_src[n * NH + h] = ps;
      a_dst[n * NH + h] = pd;
    }
  }
}

// ---------------- CSR build: histogram, scan, scatter ----------------
__global__ __launch_bounds__(256) void hist_kernel(const int* __restrict__ dst,
                                                   int* __restrict__ deg, int E) {
  int i = blockIdx.x * 256 + threadIdx.x;
  if (i < E) atomicAdd(&deg[dst[i]], 1);
}

__global__ __launch_bounds__(256) void scan_kernel(const int* __restrict__ deg,
                                                   int* __restrict__ off,
                                                   int* __restrict__ cursor, int n) {
  __shared__ int buf[256];
  __shared__ int carry;
  int t = threadIdx.x;
  if (t == 0) carry = 0;
  __syncthreads();
  for (int base = 0; base < n; base += 256) {
    int i = base + t;
    int v = (i < n) ? deg[i] : 0;
    buf[t] = v;
    __syncthreads();
    for (int ofs = 1; ofs < 256; ofs <<= 1) {
      int tv = (t >= ofs) ? buf[t - ofs] : 0;
      __syncthreads();
      buf[t] += tv;
      __syncthreads();
    }
    int excl = buf[t] - v + carry;
    if (i < n) { off[i] = excl; cursor[i] = excl; }
    __syncthreads();
    if (t == 255) carry += buf[255];
    __syncthreads();
  }
  if (t == 0) off[n] = carry;
}

__global__ __launch_bounds__(256) void scatter_kernel(const int* __restrict__ src,
                                                      const int* __restrict__ dst,
                                                      int* __restrict__ cursor,
                                                      int* __restrict__ eid_sorted,
                                                      int* __restrict__ src_sorted, int E) {
  int i = blockIdx.x * 256 + threadIdx.x;
  if (i < E) {
    int d = dst[i];
    int pos = atomicAdd(&cursor[d], 1);
    eid_sorted[pos] = i;
    src_sorted[pos] = src[i];
  }
}

// ------- per-dst-node: softmax over incoming edges + weighted aggregation -------
__global__ __launch_bounds__(256) void node_kernel(
    const int* __restrict__ off, const int* __restrict__ eid_sorted,
    const int* __restrict__ src_sorted, const float* __restrict__ a_src,
    const float* __restrict__ a_dst, const float* __restrict__ xp,
    const float* __restrict__ bias, float* __restrict__ x1,
    float* __restrict__ alpha_out) {
  int n = blockIdx.x;
  int tid = threadIdx.x;
  int lane = tid & 63, wv = tid >> 6;
  int beg = off[n], end = off[n + 1];
  int deg = end - beg;
  float bv = bias[tid];
  if (deg == 0) { x1[(size_t)n * HC + tid] = bv; return; }

  __shared__ float m_s[NH], d_s[NH];
  __shared__ float alpha_lds[CH * NH];
  __shared__ int src_lds[CH];

  // Phase A: wave wv computes (max, sum-exp) for head wv via online softmax
  {
    int h = wv;
    float adst = a_dst[n * NH + h];
    float m = -INFINITY, s = 0.f;
    for (int i = lane; i < deg; i += 64) {
      int sidx = src_sorted[beg + i];
      float l = a_src[sidx * NH + h] + adst;
      l = (l >= 0.f) ? l : 0.2f * l;
      if (l > m) { s = s * __expf(m - l) + 1.f; m = l; }
      else s += __expf(l - m);
    }
#pragma unroll
    for (int o = 32; o > 0; o >>= 1) {
      float m2 = __shfl_xor(m, o);
      float s2 = __shfl_xor(s, o);
      float M = fmaxf(m, m2);
      float sa = (m > -INFINITY) ? s * __expf(m - M) : 0.f;
      float sb = (m2 > -INFINITY) ? s2 * __expf(m2 - M) : 0.f;
      m = M; s = sa + sb;
    }
    if (lane == 0) { m_s[h] = m; d_s[h] = s + 1e-16f; }
  }
  __syncthreads();

  float acc = 0.f;
  int h_t = tid >> 6;
  for (int c0 = 0; c0 < deg; c0 += CH) {
    int clen = min(CH, deg - c0);
    // compute alphas for this chunk; write to output + LDS
    for (int idx = tid; idx < clen * NH; idx += 256) {
      int i = idx >> 2, h = idx & 3;
      int g = beg + c0 + i;
      int sidx = src_sorted[g];
      float l = a_src[sidx * NH + h] + a_dst[n * NH + h];
      l = (l >= 0.f) ? l : 0.2f * l;
      float a = __expf(l - m_s[h]) / d_s[h];
      alpha_lds[i * NH + h] = a;
      alpha_out[(size_t)eid_sorted[g] * NH + h] = a;
      if (h == 0) src_lds[i] = sidx;
    }
    __syncthreads();
    for (int i = 0; i < clen; ++i) {
      acc = fmaf(alpha_lds[i * NH + h_t], xp[(size_t)src_lds[i] * HC + tid], acc);
    }
    __syncthreads();
  }
  x1[(size_t)n * HC + tid] = acc + bv;
}

// ---------------- BatchNorm passes ----------------
__global__ __launch_bounds__(256) void bn_stats1_kernel(const float* __restrict__ x1,
                                                        float* __restrict__ sums, int N) {
  int t = threadIdx.x;
  int r0 = blockIdx.x * BROWS;
  int rend = min(r0 + BROWS, N);
  float s = 0.f, q = 0.f;
  for (int r = r0; r < rend; ++r) {
    float v = x1[(size_t)r * HC + t];
    s += v; q = fmaf(v, v, q);
  }
  atomicAdd(&sums[t], s);
  atomicAdd(&sums[HC + t], q);
}

__global__ __launch_bounds__(256) void bn_apply_kernel(
    const float* __restrict__ x1, const float* __restrict__ sums,
    const float* __restrict__ gamma, const float* __restrict__ beta,
    float* __restrict__ y, float* __restrict__ sums2, int N) {
  int t = threadIdx.x;
  float mu = sums[t] * (1.f / N);
  float var = sums[HC + t] * (1.f / N) - mu * mu;
  float inv = rsqrtf(var + 1e-5f);
  float g = gamma[t], b = beta[t];
  int r0 = blockIdx.x * BROWS;
  int rend = min(r0 + BROWS, N);
  float s = 0.f, q = 0.f;
  for (int r = r0; r < rend; ++r) {
    float v = x1[(size_t)r * HC + t];
    float x2 = fmaf((v - mu) * inv, g, b);
    float e = x2 > 0.f ? x2 : expm1f(x2);
    y[(size_t)r * HC + t] = e;
    s += e; q = fmaf(e, e, q);
  }
  atomicAdd(&sums2[t], s);
  atomicAdd(&sums2[HC + t], q);
}

__global__ __launch_bounds__(256) void bn_final_kernel(
    const float* __restrict__ y, const float* __restrict__ sums2,
    const float* __restrict__ gamma, const float* __restrict__ beta,
    float* __restrict__ out, int N) {
  int t = threadIdx.x;
  float mu = sums2[t] * (1.f / N);
  float var = sums2[HC + t] * (1.f / N) - mu * mu;
  float inv = rsqrtf(var + 1e-5f);
  float g = gamma[t], b = beta[t];
  int h = t >> 6, c = t & 63;
  int r0 = blockIdx.x * BROWS;
  int rend = min(r0 + BROWS, N);
  for (int r = r0; r < rend; ++r) {
    float v = y[(size_t)r * HC + t];
    out[(size_t)h * N * 64 + (size_t)r * 64 + c] = fmaf((v - mu) * inv, g, b);
  }
}

extern "C" void kernel_launch(void* const* d_in, const int* in_sizes, int n_in,
                              void* d_out, int out_size, void* d_ws, size_t ws_size,
                              hipStream_t stream) {
  const float* x     = (const float*)d_in[0];
  const int*   edge  = (const int*)d_in[1];
  const float* W     = (const float*)d_in[2];
  const float* att_s = (const float*)d_in[3];
  const float* att_d = (const float*)d_in[4];
  const float* bias  = (const float*)d_in[5];
  const float* gamma = (const float*)d_in[6];
  const float* beta  = (const float*)d_in[7];

  int N = in_sizes[0] / INDIM;
  int E = in_sizes[1] / 2;
  const int* src = edge;
  const int* dst = edge + E;

  char* ws = (char*)d_ws;
  size_t o = 0;
  auto alloc = [&](size_t bytes) {
    void* p = ws + o;
    o += (bytes + 255) & ~(size_t)255;
    return p;
  };
  float* xp         = (float*)alloc((size_t)N * HC * 4);  // reused as y later
  float* x1         = (float*)alloc((size_t)N * HC * 4);
  float* a_src      = (float*)alloc((size_t)N * NH * 4);
  float* a_dst      = (float*)alloc((size_t)N * NH * 4);
  int*   deg        = (int*)alloc((size_t)N * 4);
  int*   off        = (int*)alloc((size_t)(N + 1) * 4);
  int*   cursor     = (int*)alloc((size_t)N * 4);
  int*   eid_sorted = (int*)alloc((size_t)E * 4);
  int*   src_sorted = (int*)alloc((size_t)E * 4);
  float* sums1      = (float*)alloc(2 * HC * 4);
  float* sums2      = (float*)alloc(2 * HC * 4);
  float* y = xp;  // xp dead after node_kernel; safe reuse

  float* out_heads = (float*)d_out;
  float* out_alpha = out_heads + (size_t)NH * N * 64;

  hipMemsetAsync(deg, 0, (size_t)N * 4, stream);
  hipMemsetAsync(sums1, 0, 2 * HC * 4, stream);
  hipMemsetAsync(sums2, 0, 2 * HC * 4, stream);

  gemm_kernel<<<(N + 31) / 32, 256, 0, stream>>>(x, W, xp, N);
  att_kernel<<<(N + 3) / 4, 256, 0, stream>>>(xp, att_s, att_d, a_src, a_dst, N);
  hist_kernel<<<(E + 255) / 256, 256, 0, stream>>>(dst, deg, E);
  scan_kernel<<<1, 256, 0, stream>>>(deg, off, cursor, N);
  scatter_kernel<<<(E + 255) / 256, 256, 0, stream>>>(src, dst, cursor, eid_sorted, src_sorted, E);
  node_kernel<<<N, 256, 0, stream>>>(off, eid_sorted, src_sorted, a_src, a_dst, xp, bias, x1, out_alpha);
  int bnb = (N + BROWS - 1) / BROWS;
  bn_stats1_kernel<<<bnb, 256, 0, stream>>>(x1, sums1, N);
  bn_apply_kernel<<<bnb, 256, 0, stream>>>(x1, sums1, gamma, beta, y, sums2, N);
  bn_final_kernel<<<bnb, 256, 0, stream>>>(y, sums2, gamma, beta, out_heads, N);
}

// Round 3
// 204.998 us; speedup vs baseline: 1.1142x; 1.1142x over previous
//
#include <hip/hip_runtime.h>
#include <math.h>

#define INDIM 128
#define HC 256
#define NH 4
#define CH 256
#define BROWS 40

// ------- GEMM + fused attention coeffs: xp = x@W, a_src/a_dst [N,H] -------
__global__ __launch_bounds__(256) void gemm_att_kernel(
    const float* __restrict__ x, const float* __restrict__ W,
    const float* __restrict__ att_s, const float* __restrict__ att_d,
    float* __restrict__ xp, float* __restrict__ a_src,
    float* __restrict__ a_dst, int N) {
  constexpr int GN = 32;
  __shared__ float xs[GN * INDIM];
  int n0 = blockIdx.x * GN;
  int tid = threadIdx.x;
  int nrows = min(GN, N - n0);
  if (nrows == GN) {
    const float4* xg = (const float4*)(x + (size_t)n0 * INDIM);
    float4* xs4 = (float4*)xs;
    for (int i = tid; i < GN * INDIM / 4; i += 256) xs4[i] = xg[i];
  } else {
    for (int i = tid; i < GN * INDIM; i += 256) {
      int r = i / INDIM;
      xs[i] = (r < nrows) ? x[(size_t)(n0 + r) * INDIM + (i % INDIM)] : 0.f;
    }
  }
  __syncthreads();
  float acc[GN];
#pragma unroll
  for (int j = 0; j < GN; ++j) acc[j] = 0.f;
  for (int k0 = 0; k0 < INDIM; k0 += 4) {
    float w0 = W[(size_t)(k0 + 0) * HC + tid];
    float w1 = W[(size_t)(k0 + 1) * HC + tid];
    float w2 = W[(size_t)(k0 + 2) * HC + tid];
    float w3 = W[(size_t)(k0 + 3) * HC + tid];
#pragma unroll
    for (int j = 0; j < GN; ++j) {
      float4 xv = *(const float4*)&xs[j * INDIM + k0];
      acc[j] = fmaf(xv.w, w3, fmaf(xv.z, w2, fmaf(xv.y, w1, fmaf(xv.x, w0, acc[j]))));
    }
  }
  // epilogue: store xp row-slices; wave w (=head w) reduces att dot-products
  float asv = att_s[tid], adv = att_d[tid];
  int wv = tid >> 6, lane = tid & 63;
  for (int j = 0; j < nrows; ++j) {
    xp[(size_t)(n0 + j) * HC + tid] = acc[j];
    float ps = acc[j] * asv, pd = acc[j] * adv;
#pragma unroll
    for (int o = 32; o > 0; o >>= 1) {
      ps += __shfl_xor(ps, o);
      pd += __shfl_xor(pd, o);
    }
    if (lane == 0) {
      a_src[(n0 + j) * NH + wv] = ps;
      a_dst[(n0 + j) * NH + wv] = pd;
    }
  }
}

// ---------------- CSR build: histogram, scan, scatter ----------------
__global__ __launch_bounds__(256) void hist_kernel(const int* __restrict__ dst,
                                                   int* __restrict__ deg, int E) {
  int i = blockIdx.x * 256 + threadIdx.x;
  if (i < E) atomicAdd(&deg[dst[i]], 1);
}

// single block; thread-serial chunks + one block-scan of 256 partials
__global__ __launch_bounds__(256) void scan_kernel(const int* __restrict__ deg,
                                                   int* __restrict__ off,
                                                   int* __restrict__ cursor, int n) {
  __shared__ int buf[256];
  int t = threadIdx.x;
  int chunk = (n + 255) / 256;
  int b0 = min(t * chunk, n), b1 = min(b0 + chunk, n);
  int s = 0;
  for (int i = b0; i < b1; ++i) s += deg[i];
  buf[t] = s;
  __syncthreads();
  for (int ofs = 1; ofs < 256; ofs <<= 1) {
    int v = (t >= ofs) ? buf[t - ofs] : 0;
    __syncthreads();
    buf[t] += v;
    __syncthreads();
  }
  int run = buf[t] - s;  // exclusive prefix of this chunk
  for (int i = b0; i < b1; ++i) {
    off[i] = run;
    cursor[i] = run;
    run += deg[i];
  }
  if (t == 255) off[n] = buf[255];
}

__global__ __launch_bounds__(256) void scatter_kernel(const int* __restrict__ src,
                                                      const int* __restrict__ dst,
                                                      int* __restrict__ cursor,
                                                      int* __restrict__ eid_sorted,
                                                      int* __restrict__ src_sorted, int E) {
  int i = blockIdx.x * 256 + threadIdx.x;
  if (i < E) {
    int d = dst[i];
    int pos = atomicAdd(&cursor[d], 1);
    eid_sorted[pos] = i;
    src_sorted[pos] = src[i];
  }
}

// ------- per-dst-node: softmax over incoming edges + weighted aggregation -------
__global__ __launch_bounds__(256) void node_kernel(
    const int* __restrict__ off, const int* __restrict__ eid_sorted,
    const int* __restrict__ src_sorted, const float* __restrict__ a_src,
    const float* __restrict__ a_dst, const float* __restrict__ xp,
    const float* __restrict__ bias, float* __restrict__ x1,
    float* __restrict__ alpha_out) {
  int n = blockIdx.x;
  int tid = threadIdx.x;
  int lane = tid & 63, wv = tid >> 6;
  int beg = off[n], end = off[n + 1];
  int deg = end - beg;
  float bv = bias[tid];
  if (deg == 0) { x1[(size_t)n * HC + tid] = bv; return; }

  __shared__ float m_s[NH], d_s[NH];
  __shared__ float alpha_lds[CH * NH];
  __shared__ int src_lds[CH];

  // Phase A: wave wv computes (max, sum-exp) for head wv via online softmax
  {
    int h = wv;
    float adst = a_dst[n * NH + h];
    float m = -INFINITY, s = 0.f;
    for (int i = lane; i < deg; i += 64) {
      int sidx = src_sorted[beg + i];
      float l = a_src[sidx * NH + h] + adst;
      l = (l >= 0.f) ? l : 0.2f * l;
      if (l > m) { s = s * __expf(m - l) + 1.f; m = l; }
      else s += __expf(l - m);
    }
#pragma unroll
    for (int o = 32; o > 0; o >>= 1) {
      float m2 = __shfl_xor(m, o);
      float s2 = __shfl_xor(s, o);
      float M = fmaxf(m, m2);
      float sa = (m > -INFINITY) ? s * __expf(m - M) : 0.f;
      float sb = (m2 > -INFINITY) ? s2 * __expf(m2 - M) : 0.f;
      m = M; s = sa + sb;
    }
    if (lane == 0) { m_s[h] = m; d_s[h] = s + 1e-16f; }
  }
  __syncthreads();

  float m_r[NH], dinv_r[NH], adst_r[NH];
#pragma unroll
  for (int h = 0; h < NH; ++h) {
    m_r[h] = m_s[h];
    dinv_r[h] = 1.0f / d_s[h];
    adst_r[h] = a_dst[n * NH + h];
  }

  float acc = 0.f;
  int h_t = tid >> 6;
  for (int c0 = 0; c0 < deg; c0 += CH) {
    int clen = min(CH, deg - c0);
    // one edge per thread: compute all 4 head alphas, float4 stores
    if (tid < clen) {
      int g = beg + c0 + tid;
      int sidx = src_sorted[g];
      src_lds[tid] = sidx;
      float4 av;
      float* ap = (float*)&av;
#pragma unroll
      for (int h = 0; h < NH; ++h) {
        float l = a_src[sidx * NH + h] + adst_r[h];
        l = (l >= 0.f) ? l : 0.2f * l;
        ap[h] = __expf(l - m_r[h]) * dinv_r[h];
      }
      *(float4*)&alpha_lds[tid * NH] = av;
      *(float4*)&alpha_out[(size_t)eid_sorted[g] * NH] = av;
    }
    __syncthreads();
    for (int i = 0; i < clen; ++i) {
      acc = fmaf(alpha_lds[i * NH + h_t], xp[(size_t)src_lds[i] * HC + tid], acc);
    }
    __syncthreads();
  }
  x1[(size_t)n * HC + tid] = acc + bv;
}

// ---------------- BatchNorm passes ----------------
__global__ __launch_bounds__(256) void bn_stats1_kernel(const float* __restrict__ x1,
                                                        float* __restrict__ sums, int N) {
  int t = threadIdx.x;
  int r0 = blockIdx.x * BROWS;
  int rend = min(r0 + BROWS, N);
  float s = 0.f, q = 0.f;
  for (int r = r0; r < rend; ++r) {
    float v = x1[(size_t)r * HC + t];
    s += v; q = fmaf(v, v, q);
  }
  atomicAdd(&sums[t], s);
  atomicAdd(&sums[HC + t], q);
}

__global__ __launch_bounds__(256) void bn_apply_kernel(
    const float* __restrict__ x1, const float* __restrict__ sums,
    const float* __restrict__ gamma, const float* __restrict__ beta,
    float* __restrict__ y, float* __restrict__ sums2, int N) {
  int t = threadIdx.x;
  float mu = sums[t] * (1.f / N);
  float var = sums[HC + t] * (1.f / N) - mu * mu;
  float inv = rsqrtf(var + 1e-5f);
  float g = gamma[t], b = beta[t];
  int r0 = blockIdx.x * BROWS;
  int rend = min(r0 + BROWS, N);
  float s = 0.f, q = 0.f;
  for (int r = r0; r < rend; ++r) {
    float v = x1[(size_t)r * HC + t];
    float x2 = fmaf((v - mu) * inv, g, b);
    float e = x2 > 0.f ? x2 : expm1f(x2);
    y[(size_t)r * HC + t] = e;
    s += e; q = fmaf(e, e, q);
  }
  atomicAdd(&sums2[t], s);
  atomicAdd(&sums2[HC + t], q);
}

__global__ __launch_bounds__(256) void bn_final_kernel(
    const float* __restrict__ y, const float* __restrict__ sums2,
    const float* __restrict__ gamma, const float* __restrict__ beta,
    float* __restrict__ out, int N) {
  int t = threadIdx.x;
  float mu = sums2[t] * (1.f / N);
  float var = sums2[HC + t] * (1.f / N) - mu * mu;
  float inv = rsqrtf(var + 1e-5f);
  float g = gamma[t], b = beta[t];
  int h = t >> 6, c = t & 63;
  int r0 = blockIdx.x * BROWS;
  int rend = min(r0 + BROWS, N);
  for (int r = r0; r < rend; ++r) {
    float v = y[(size_t)r * HC + t];
    out[(size_t)h * N * 64 + (size_t)r * 64 + c] = fmaf((v - mu) * inv, g, b);
  }
}

extern "C" void kernel_launch(void* const* d_in, const int* in_sizes, int n_in,
                              void* d_out, int out_size, void* d_ws, size_t ws_size,
                              hipStream_t stream) {
  const float* x     = (const float*)d_in[0];
  const int*   edge  = (const int*)d_in[1];
  const float* W     = (const float*)d_in[2];
  const float* att_s = (const float*)d_in[3];
  const float* att_d = (const float*)d_in[4];
  const float* bias  = (const float*)d_in[5];
  const float* gamma = (const float*)d_in[6];
  const float* beta  = (const float*)d_in[7];

  int N = in_sizes[0] / INDIM;
  int E = in_sizes[1] / 2;
  const int* src = edge;
  const int* dst = edge + E;

  char* ws = (char*)d_ws;
  size_t o = 0;
  auto alloc = [&](size_t bytes) {
    void* p = ws + o;
    o += (bytes + 255) & ~(size_t)255;
    return p;
  };
  float* xp         = (float*)alloc((size_t)N * HC * 4);  // reused as y later
  float* x1         = (float*)alloc((size_t)N * HC * 4);
  float* a_src      = (float*)alloc((size_t)N * NH * 4);
  float* a_dst      = (float*)alloc((size_t)N * NH * 4);
  // zero-init region: deg + sums1 + sums2 contiguous -> single memset
  char*  zbase      = (char*)alloc(0);
  int*   deg        = (int*)alloc((size_t)N * 4);
  float* sums1      = (float*)alloc(2 * HC * 4);
  float* sums2      = (float*)alloc(2 * HC * 4);
  size_t zbytes     = (size_t)((char*)alloc(0) - zbase);
  int*   off        = (int*)alloc((size_t)(N + 1) * 4);
  int*   cursor     = (int*)alloc((size_t)N * 4);
  int*   eid_sorted = (int*)alloc((size_t)E * 4);
  int*   src_sorted = (int*)alloc((size_t)E * 4);
  float* y = xp;  // xp dead after node_kernel; safe reuse

  float* out_heads = (float*)d_out;
  float* out_alpha = out_heads + (size_t)NH * N * 64;

  hipMemsetAsync(zbase, 0, zbytes, stream);

  gemm_att_kernel<<<(N + 31) / 32, 256, 0, stream>>>(x, W, att_s, att_d, xp, a_src, a_dst, N);
  hist_kernel<<<(E + 255) / 256, 256, 0, stream>>>(dst, deg, E);
  scan_kernel<<<1, 256, 0, stream>>>(deg, off, cursor, N);
  scatter_kernel<<<(E + 255) / 256, 256, 0, stream>>>(src, dst, cursor, eid_sorted, src_sorted, E);
  node_kernel<<<N, 256, 0, stream>>>(off, eid_sorted, src_sorted, a_src, a_dst, xp, bias, x1, out_alpha);
  int bnb = (N + BROWS - 1) / BROWS;
  bn_stats1_kernel<<<bnb, 256, 0, stream>>>(x1, sums1, N);
  bn_apply_kernel<<<bnb, 256, 0, stream>>>(x1, sums1, gamma, beta, y, sums2, N);
  bn_final_kernel<<<bnb, 256, 0, stream>>>(y, sums2, gamma, beta, out_heads, N);
}